// Round 16
// baseline (83.200 us; speedup 1.0000x reference)
//
#include <hip/hip_runtime.h>
#include <math.h>

#define B_ 2
#define L_ 2048
#define C_ 1024
#define H_ 16
#define D_ 64
#define BH_ (B_*H_)      // 32
#define M_ (B_*L_)       // 4096
#define N_ (3*C_)        // 3072
#define NW_ 3200         // Wcat rows: 3072 proj + 16 lrw + 112 pad (poison, unused)
#define K_ C_            // 1024
#define EPS_ 1e-6f
#define NCHUNK_ 16       // L-split for G partials
#define LDT_ 136         // padded LDS row stride (shorts): 272B, 16B-aligned, 2-way banks
#define WTS_ 72          // padded Wt stride (shorts): 144B, 16B-aligned, 2-way banks

typedef unsigned short ushort_t;
typedef short short8 __attribute__((ext_vector_type(8)));
typedef float f32x4 __attribute__((ext_vector_type(4)));
typedef unsigned short ushort4_t __attribute__((ext_vector_type(4)));

__device__ __forceinline__ ushort_t f2bf(float f) {
    union { float f; unsigned u; } v; v.f = f;
    unsigned r = v.u + 0x7FFFu + ((v.u >> 16) & 1u);
    return (ushort_t)(r >> 16);
}
__device__ __forceinline__ float bf2f(ushort_t h) {
    union { unsigned u; float f; } v; v.u = ((unsigned)h) << 16;
    return v.f;
}

__device__ __forceinline__ void gload16(const void* g, void* l) {
    __builtin_amdgcn_global_load_lds(
        (const __attribute__((address_space(1))) void*)g,
        (__attribute__((address_space(3))) void*)l, 16, 0, 0);
}

// ---------------- cast hs+weights -> bf16, W1 transpose (eta moved to gemm) ----------------
// blocks 0..2047: two hs rows, pure streaming cast; 2048..2819: weight cast
// (slot2 = Wv - Wk; slot3 head rows 3072..3087 = lrw); 2820..2835: W1^T.
__global__ __launch_bounds__(256) void cast_w(
    const float* __restrict__ hs, const float* __restrict__ Wq,
    const float* __restrict__ Wk, const float* __restrict__ Wv,
    const float* __restrict__ W1, const float* __restrict__ lrw,
    ushort_t* __restrict__ hsB, ushort_t* __restrict__ Wcat,
    ushort_t* __restrict__ W1tg, float* __restrict__ W1tf) {
    const int bid = blockIdx.x, t = threadIdx.x;
    if (bid < 2048) {
        const int iA = bid * 2;
        #pragma unroll
        for (int rr = 0; rr < 2; ++rr) {
            const float* r = hs + (size_t)(iA + rr) * C_;
            f32x4 a = *(const f32x4*)(r + t * 4);
            ushort4_t o;
            o.x = f2bf(a.x); o.y = f2bf(a.y); o.z = f2bf(a.z); o.w = f2bf(a.w);
            *(ushort4_t*)(hsB + (size_t)(iA + rr) * C_ + t * 4) = o;
        }
    } else if (bid < 2820) {
        const int wb = bid - 2048;   // 0..771
        #pragma unroll
        for (int ii = 0; ii < 4; ++ii) {
            int cid = wb * 1024 + ii * 256 + t;      // 0..790527
            int m = cid >> 18, r = cid & ((1 << 18) - 1);
            f32x4 v;
            if (m == 0)      v = *(const f32x4*)(Wq + (size_t)r * 4);
            else if (m == 1) v = *(const f32x4*)(Wk + (size_t)r * 4);
            else if (m == 2) {
                f32x4 vv = *(const f32x4*)(Wv + (size_t)r * 4);
                f32x4 vk = *(const f32x4*)(Wk + (size_t)r * 4);
                v.x = vv.x - vk.x; v.y = vv.y - vk.y;
                v.z = vv.z - vk.z; v.w = vv.w - vk.w;
            } else {
                v = *(const f32x4*)(lrw + (size_t)r * 4);   // 16 rows of lrw
            }
            ushort4_t o;
            o.x = f2bf(v.x); o.y = f2bf(v.y); o.z = f2bf(v.z); o.w = f2bf(v.w);
            *(ushort4_t*)(Wcat + (size_t)m * (C_ * C_) + (size_t)r * 4) = o;
        }
    } else {
        const int h = bid - 2820;    // 0..15
        __shared__ float Wl[64 * 65];
        #pragma unroll
        for (int p = 0; p < 4; ++p) {
            int i4 = p * 256 + t;
            int e = i4 >> 4, f0 = (i4 & 15) * 4;
            f32x4 v = *(const f32x4*)(W1 + (size_t)h * 4096 + e * 64 + f0);
            Wl[(f0 + 0) * 65 + e] = v.x;
            Wl[(f0 + 1) * 65 + e] = v.y;
            Wl[(f0 + 2) * 65 + e] = v.z;
            Wl[(f0 + 3) * 65 + e] = v.w;
        }
        __syncthreads();
        #pragma unroll
        for (int p = 0; p < 16; ++p) {
            int flat = p * 256 + t;           // f*64 + e
            float v = Wl[(flat >> 6) * 65 + (flat & 63)];
            W1tf[(size_t)h * 4096 + flat] = v;
            W1tg[(size_t)h * 4096 + flat] = f2bf(v);
        }
    }
}

// ---------------- projection GEMM: [4096,1024] @ Wcat[3200,1024]^T ----------------
// R4-exact structure (BK=32, 16 KB LDS, one K-tile/barrier pair, 2-way
// pre-swizzle, scattered 2B stores). bn 0..23: XQ/XK/XT. bn 24: eta tile —
// cols 0..15 are lrw rows; epilogue = sigmoid(acc+lrb)/64 (R11 proved
// absmax unaffected; R11's regression was the confounded 34.8KB gemm).
__global__ __launch_bounds__(256) void gemm_qkv(
    const ushort_t* __restrict__ A, const ushort_t* __restrict__ Bc,
    ushort_t* __restrict__ XQ, ushort_t* __restrict__ XK,
    ushort_t* __restrict__ XT, const float* __restrict__ lrb,
    float* __restrict__ eta) {
    __shared__ __align__(16) ushort_t Al[128 * 32];
    __shared__ __align__(16) ushort_t Bl[128 * 32];
    const int bm = blockIdx.x, bn = blockIdx.y;
    const int t = threadIdx.x, w = t >> 6, lane = t & 63;
    const int wr = w >> 1, wc = w & 1;
    const int la15 = lane & 15, la4 = lane >> 4;
    f32x4 acc[4][4];
    #pragma unroll
    for (int a = 0; a < 4; a++)
        #pragma unroll
        for (int b = 0; b < 4; b++)
            #pragma unroll
            for (int j = 0; j < 4; j++) acc[a][b][j] = 0.f;

    const int ci0 = w * 64 + lane;
    const int xread = (la15 >> 1) & 3;               // read-side swizzle (const/thread)
    const int uslot = la4 ^ xread;                   // swizzled 16B unit for frags

    for (int kt = 0; kt < K_ / 32; ++kt) {
        __syncthreads();
        #pragma unroll
        for (int q = 0; q < 2; ++q) {
            int ci = q * 256 + ci0;
            int r = ci >> 2, kc = ci & 3;
            int kcp = kc ^ ((r >> 1) & 3);           // pre-swizzled source column
            gload16(A + (size_t)(bm * 128 + r) * K_ + kt * 32 + kcp * 8,
                    &Al[q * 2048 + w * 512]);
            gload16(Bc + (size_t)(bn * 128 + r) * K_ + kt * 32 + kcp * 8,
                    &Bl[q * 2048 + w * 512]);
        }
        __syncthreads();
        short8 af[4], bfv[4];
        #pragma unroll
        for (int mf = 0; mf < 4; ++mf)
            af[mf] = *(const short8*)&Al[(wr * 64 + mf * 16 + la15) * 32 + uslot * 8];
        #pragma unroll
        for (int nf = 0; nf < 4; ++nf)
            bfv[nf] = *(const short8*)&Bl[(wc * 64 + nf * 16 + la15) * 32 + uslot * 8];
        #pragma unroll
        for (int mf = 0; mf < 4; ++mf)
            #pragma unroll
            for (int nf = 0; nf < 4; ++nf)
                acc[mf][nf] = __builtin_amdgcn_mfma_f32_16x16x32_bf16(
                    af[mf], bfv[nf], acc[mf][nf], 0, 0, 0);
    }

    if (bn == 24) {
        // eta tile: cols 0..15 (nf==0, wc==0 waves) = heads; sigmoid epilogue
        if (wc == 0) {
            const float bb = lrb[la15];
            #pragma unroll
            for (int mf = 0; mf < 4; ++mf)
                #pragma unroll
                for (int rg = 0; rg < 4; ++rg) {
                    int i = bm * 128 + wr * 64 + mf * 16 + la4 * 4 + rg;
                    int b = i >> 11, l = i & (L_ - 1);
                    float x = acc[mf][0][rg] + bb;
                    eta[((size_t)(b * H_ + la15)) * L_ + l] =
                        (1.f / (1.f + expf(-x))) * (1.0f / 64.0f);
                }
        }
        return;
    }

    const int jbase = bn * 128;
    const int mtx = jbase >> 10;
    ushort_t* dst = (mtx == 0) ? XQ : (mtx == 1 ? XK : XT);
    #pragma unroll
    for (int mf = 0; mf < 4; ++mf)
        #pragma unroll
        for (int nf = 0; nf < 4; ++nf)
            #pragma unroll
            for (int rg = 0; rg < 4; ++rg) {
                int i = bm * 128 + wr * 64 + mf * 16 + (la4 << 2) + rg;
                int j = (jbase & 1023) + wc * 64 + nf * 16 + la15;
                int b = i >> 11, l = i & (L_ - 1);
                int h = j >> 6, d = j & 63;
                dst[((size_t)(b * H_ + h) * L_ + l) * D_ + d] = f2bf(acc[mf][nf][rg]);
            }
}

// ---------------- K2 fused (8 waves, 16 rows/wave):
//                  Z1 = XK@W1+b1 (W1^T frags from L2), LN-L2-bwd (target = XT,
//                  var = E[x^2]-mu^2), eg = eta*grad, GpT = eg^T@XK, bsump ----
__global__ __launch_bounds__(512) void k2_grad2(
    const ushort_t* __restrict__ XK, const ushort_t* __restrict__ XT,
    const ushort_t* __restrict__ W1tg, const float* __restrict__ b1,
    const float* __restrict__ tw, const float* __restrict__ tb,
    const float* __restrict__ eta, float* __restrict__ GpT,
    float* __restrict__ bsump) {
    __shared__ __align__(16) ushort_t xkt[64 * LDT_];   // XK^T (d-major, l-contig)
    __shared__ __align__(16) ushort_t egl[64 * LDT_];   // eg^T (d-major, l-contig)
    __shared__ float b1s[64], gs[64], bes[64];
    __shared__ float sred[8][64];
    const int bh = blockIdx.y, lt = blockIdx.x;
    const int h = bh & (H_ - 1);
    const int t = threadIdx.x, w = t >> 6, lane = t & 63;
    const int la15 = lane & 15, la4 = lane >> 4;
    if (t < 64) { b1s[t] = b1[h * 64 + t]; gs[t] = tw[h * 64 + t]; bes[t] = tb[h * 64 + t]; }
    __syncthreads();

    const ushort_t* xk = XK + (size_t)bh * L_ * D_;
    const ushort_t* xt = XT + (size_t)bh * L_ * D_;
    const ushort_t* w1g = W1tg + (size_t)h * 4096;
    const int l0 = lt * 128 + w * 16;    // global l base for this wave (16 rows)
    const int llw = w * 16;              // local l base

    f32x4 acc[4];
    #pragma unroll
    for (int nf = 0; nf < 4; nf++) {
        float bv = b1s[nf * 16 + la15];
        #pragma unroll
        for (int j = 0; j < 4; j++) acc[nf][j] = bv;
    }
    #pragma unroll
    for (int ks = 0; ks < 2; ++ks) {
        short8 af, bfv[4];
        const int d0 = ks * 32 + la4 * 8;
        af = *(const short8*)&xk[(size_t)(l0 + la15) * D_ + d0];
        {
            const int ll = llw + la15;
            #pragma unroll
            for (int jj = 0; jj < 8; jj++)
                xkt[(d0 + jj) * LDT_ + ll] = (ushort_t)af[jj];
        }
        #pragma unroll
        for (int nf = 0; nf < 4; nf++)
            bfv[nf] = *(const short8*)&w1g[(nf * 16 + la15) * 64 + d0];
        #pragma unroll
        for (int nf = 0; nf < 4; nf++)
            acc[nf] = __builtin_amdgcn_mfma_f32_16x16x32_bf16(
                af, bfv[nf], acc[nf], 0, 0, 0);
    }

    const float* etap = eta + (size_t)bh * L_;
    float accbs[4] = {0.f, 0.f, 0.f, 0.f};
    #pragma unroll
    for (int rg = 0; rg < 4; ++rg) {
        int lrow = l0 + (la4 << 2) + rg;
        int llr  = llw + (la4 << 2) + rg;
        float x[4], xh[4], gh[4];
        #pragma unroll
        for (int nf = 0; nf < 4; nf++) x[nf] = acc[nf][rg];
        // concurrent sum / sumsq chains (var = E[x^2] - mu^2)
        float s = x[0] + x[1] + x[2] + x[3];
        float q = x[0]*x[0] + x[1]*x[1] + x[2]*x[2] + x[3]*x[3];
        s += __shfl_xor(s, 1, 64); q += __shfl_xor(q, 1, 64);
        s += __shfl_xor(s, 2, 64); q += __shfl_xor(q, 2, 64);
        s += __shfl_xor(s, 4, 64); q += __shfl_xor(q, 4, 64);
        s += __shfl_xor(s, 8, 64); q += __shfl_xor(q, 8, 64);
        float mu = s * (1.f / 64.f);
        float var = q * (1.f / 64.f) - mu * mu;
        float inv = 1.f / sqrtf(var + EPS_);
        float s1 = 0.f, s2 = 0.f;
        #pragma unroll
        for (int nf = 0; nf < 4; nf++) {
            int d = nf * 16 + la15;
            xh[nf] = (x[nf] - mu) * inv;
            float tgt = bf2f(xt[(size_t)lrow * D_ + d]);
            float g = gs[d];
            gh[nf] = (g * xh[nf] + bes[d] - tgt) * g;
            s1 += gh[nf]; s2 += gh[nf] * xh[nf];
        }
        s1 += __shfl_xor(s1, 1, 64); s2 += __shfl_xor(s2, 1, 64);
        s1 += __shfl_xor(s1, 2, 64); s2 += __shfl_xor(s2, 2, 64);
        s1 += __shfl_xor(s1, 4, 64); s2 += __shfl_xor(s2, 4, 64);
        s1 += __shfl_xor(s1, 8, 64); s2 += __shfl_xor(s2, 8, 64);
        float m1 = s1 * (1.f / 64.f), m2 = s2 * (1.f / 64.f);
        float el = etap[lrow];
        #pragma unroll
        for (int nf = 0; nf < 4; nf++) {
            int d = nf * 16 + la15;
            float egv = el * ((gh[nf] - m1 - xh[nf] * m2) * inv);
            accbs[nf] += egv;
            egl[d * LDT_ + llr] = f2bf(egv);
        }
    }
    // wave-local bsum partial: combine the 4 row-groups (lane>>4)
    #pragma unroll
    for (int nf = 0; nf < 4; nf++) {
        accbs[nf] += __shfl_xor(accbs[nf], 16, 64);
        accbs[nf] += __shfl_xor(accbs[nf], 32, 64);
    }
    if (lane < 16)
        #pragma unroll
        for (int nf = 0; nf < 4; nf++) sred[w][nf * 16 + lane] = accbs[nf];
    __syncthreads();

    // G^T partial: GpT[f][e] = sum_l eg[l][f] * XK[l][e]; waves 0..3 only.
    if (w < 4) {
        f32x4 aG[4];
        #pragma unroll
        for (int nf = 0; nf < 4; nf++)
            #pragma unroll
            for (int j = 0; j < 4; j++) aG[nf][j] = 0.f;
        #pragma unroll
        for (int ks = 0; ks < 4; ++ks) {
            const int ko = ks * 32 + la4 * 8;
            short8 ae = *(const short8*)&egl[(w * 16 + la15) * LDT_ + ko];
            #pragma unroll
            for (int nf = 0; nf < 4; nf++) {
                short8 be = *(const short8*)&xkt[(nf * 16 + la15) * LDT_ + ko];
                aG[nf] = __builtin_amdgcn_mfma_f32_16x16x32_bf16(ae, be, aG[nf], 0, 0, 0);
            }
        }
        float* gp = GpT + (size_t)(bh * NCHUNK_ + lt) * 4096;
        #pragma unroll
        for (int nf = 0; nf < 4; nf++)
            #pragma unroll
            for (int rg = 0; rg < 4; rg++) {
                int f = w * 16 + (la4 << 2) + rg;
                int e = nf * 16 + la15;
                gp[f * 64 + e] = aG[nf][rg];
            }
    }
    if (t < 64) {
        float s = 0.f;
        #pragma unroll
        for (int ww = 0; ww < 8; ww++) s += sred[ww][t];
        bsump[(bh * NCHUNK_ + lt) * 64 + t] = s;
    }
}

// ---------------- K2b-reduce: G = sum_c GpT, bsum = sum_c bsump (fixed order) ----
__global__ __launch_bounds__(256) void k2b_reduce(
    const float* __restrict__ GpT, const float* __restrict__ bsump,
    float* __restrict__ G, float* __restrict__ bsum) {
    const int seg = blockIdx.x, bh = blockIdx.y;   // seg in [0,8)
    const int t = threadIdx.x;
    #pragma unroll 2
    for (int ii = 0; ii < 2; ++ii) {
        int i = seg * 512 + ii * 256 + t;
        float s = 0.f;
        #pragma unroll
        for (int c = 0; c < NCHUNK_; c++)
            s += GpT[(size_t)(bh * NCHUNK_ + c) * 4096 + i];
        G[(size_t)bh * 4096 + i] = s;
    }
    if (seg == 0 && t < 64) {
        float s = 0.f;
        #pragma unroll
        for (int c = 0; c < NCHUNK_; c++)
            s += bsump[(bh * NCHUNK_ + c) * 64 + t];
        bsum[bh * 64 + t] = s;
    }
}

// ---------------- K3 (8 waves, 16 rows/wave):
//                  Wt = W1^T - G^T (linear fill, stride-72 pad),
//                  Z1b = XQ@Wt + b1bar, LN-fwd, out = XQ + LN ----------------
__global__ __launch_bounds__(512) void k3_out(
    const ushort_t* __restrict__ XQ, const float* __restrict__ W1tf,
    const float* __restrict__ G, const float* __restrict__ b1,
    const float* __restrict__ bsum, const float* __restrict__ tw,
    const float* __restrict__ tb, float* __restrict__ out) {
    __shared__ __align__(16) ushort_t Wt[64 * WTS_];
    __shared__ float b1s[64], gs[64], bes[64];
    const int bh = blockIdx.y, lt = blockIdx.x;
    const int h = bh & (H_ - 1);
    const int t = threadIdx.x, w = t >> 6, lane = t & 63;
    const int la15 = lane & 15, la4 = lane >> 4;
    for (int p = t; p < 4096; p += 512) {
        float s = W1tf[(size_t)h * 4096 + p] - G[(size_t)bh * 4096 + p];
        Wt[(p >> 6) * WTS_ + (p & 63)] = f2bf(s);
    }
    if (t < 64) {
        b1s[t] = b1[h * 64 + t] - bsum[bh * 64 + t];
        gs[t] = tw[h * 64 + t]; bes[t] = tb[h * 64 + t];
    }
    __syncthreads();

    const ushort_t* xq = XQ + (size_t)bh * L_ * D_;
    const int l0 = lt * 128 + w * 16;
    f32x4 acc[4];
    #pragma unroll
    for (int nf = 0; nf < 4; nf++) {
        float bv = b1s[nf * 16 + la15];
        #pragma unroll
        for (int j = 0; j < 4; j++) acc[nf][j] = bv;
    }
    #pragma unroll
    for (int ks = 0; ks < 2; ++ks) {
        short8 af, bfv[4];
        const int d0 = ks * 32 + la4 * 8;
        af = *(const short8*)&xq[(size_t)(l0 + la15) * D_ + d0];
        #pragma unroll
        for (int nf = 0; nf < 4; nf++)
            bfv[nf] = *(const short8*)&Wt[(nf * 16 + la15) * WTS_ + d0];
        #pragma unroll
        for (int nf = 0; nf < 4; nf++)
            acc[nf] = __builtin_amdgcn_mfma_f32_16x16x32_bf16(
                af, bfv[nf], acc[nf], 0, 0, 0);
    }

    float* outp = out + (size_t)bh * L_ * D_;
    #pragma unroll
    for (int rg = 0; rg < 4; ++rg) {
        int lrow = l0 + (la4 << 2) + rg;
        float x[4];
        #pragma unroll
        for (int nf = 0; nf < 4; nf++) x[nf] = acc[nf][rg];
        float s = x[0] + x[1] + x[2] + x[3];
        float q = x[0]*x[0] + x[1]*x[1] + x[2]*x[2] + x[3]*x[3];
        s += __shfl_xor(s, 1, 64); q += __shfl_xor(q, 1, 64);
        s += __shfl_xor(s, 2, 64); q += __shfl_xor(q, 2, 64);
        s += __shfl_xor(s, 4, 64); q += __shfl_xor(q, 4, 64);
        s += __shfl_xor(s, 8, 64); q += __shfl_xor(q, 8, 64);
        float mu = s * (1.f / 64.f);
        float var = q * (1.f / 64.f) - mu * mu;
        float inv = 1.f / sqrtf(var + EPS_);
        #pragma unroll
        for (int nf = 0; nf < 4; nf++) {
            int d = nf * 16 + la15;
            float xh = (x[nf] - mu) * inv;
            float o = gs[d] * xh + bes[d];
            float qv = bf2f(xq[(size_t)lrow * D_ + d]);
            outp[(size_t)lrow * D_ + d] = qv + o;
        }
    }
}

extern "C" void kernel_launch(void* const* d_in, const int* in_sizes, int n_in,
                              void* d_out, int out_size, void* d_ws, size_t ws_size,
                              hipStream_t stream) {
    const float* hs  = (const float*)d_in[0];
    const float* Wq  = (const float*)d_in[1];
    const float* Wk  = (const float*)d_in[2];
    const float* Wv  = (const float*)d_in[3];
    const float* W1  = (const float*)d_in[4];
    const float* b1  = (const float*)d_in[5];
    const float* tw  = (const float*)d_in[6];
    const float* tb  = (const float*)d_in[7];
    const float* lrw = (const float*)d_in[8];
    const float* lrb = (const float*)d_in[9];
    float* out = (float*)d_out;

    char* ws = (char*)d_ws;
    size_t off = 0;
    ushort_t* hsB  = (ushort_t*)(ws + off); off += (size_t)M_ * K_ * 2;   // 8 MB
    ushort_t* Wcat = (ushort_t*)(ws + off); off += (size_t)NW_ * K_ * 2;  // 6.55 MB
    ushort_t* XQ   = (ushort_t*)(ws + off); off += (size_t)M_ * C_ * 2;
    ushort_t* XK   = (ushort_t*)(ws + off); off += (size_t)M_ * C_ * 2;
    ushort_t* XT   = (ushort_t*)(ws + off); off += (size_t)M_ * C_ * 2;   // recon target
    float*    eta  = (float*)(ws + off);    off += (size_t)BH_ * L_ * 4;
    ushort_t* W1tg = (ushort_t*)(ws + off); off += (size_t)H_ * D_ * D_ * 2;  // bf16 W1^T
    float*    W1tf = (float*)(ws + off);    off += (size_t)H_ * D_ * D_ * 4;  // f32 W1^T
    float*    G    = (float*)(ws + off);    off += (size_t)BH_ * D_ * D_ * 4; // reduced G^T
    float*    bsum = (float*)(ws + off);    off += (size_t)BH_ * D_ * 4;
    // Partial buffers overlay hsB/Wcat: both dead after gemm_qkv; k2_grad2
    // writes them strictly later on the same stream.
    float*    GpT   = (float*)hsB;   // 32*16*4096*4 = 8 MB == sizeof(hsB)
    float*    bsump = (float*)Wcat;  // 128 KB << 6.55 MB

    cast_w<<<2048 + 772 + 16, 256, 0, stream>>>(hs, Wq, Wk, Wv, W1, lrw,
                                                hsB, Wcat, W1tg, W1tf);
    gemm_qkv<<<dim3(M_ / 128, 25), 256, 0, stream>>>(hsB, Wcat, XQ, XK, XT, lrb, eta);
    k2_grad2<<<dim3(L_ / 128, BH_), 512, 0, stream>>>(XK, XT, W1tg, b1, tw, tb, eta, GpT, bsump);
    k2b_reduce<<<dim3(8, BH_), 256, 0, stream>>>(GpT, bsump, G, bsum);
    k3_out<<<dim3(L_ / 128, BH_), 512, 0, stream>>>(XQ, W1tf, G, b1, bsum, tw, tb, out);
}

// Round 17
// 74.648 us; speedup vs baseline: 1.1146x; 1.1146x over previous
//
#include <hip/hip_runtime.h>
#include <math.h>

#define B_ 2
#define L_ 2048
#define C_ 1024
#define H_ 16
#define D_ 64
#define BH_ (B_*H_)      // 32
#define M_ (B_*L_)       // 4096
#define N_ (3*C_)        // 3072
#define K_ C_            // 1024
#define EPS_ 1e-6f
#define NCHUNK_ 16       // L-split for G partials
#define LDT_ 136         // padded LDS row stride (shorts): 272B, 16B-aligned, 2-way banks
#define WTS_ 72          // padded Wt stride (shorts): 144B, 16B-aligned, 2-way banks

typedef unsigned short ushort_t;
typedef short short8 __attribute__((ext_vector_type(8)));
typedef float f32x4 __attribute__((ext_vector_type(4)));
typedef unsigned short ushort4_t __attribute__((ext_vector_type(4)));

__device__ __forceinline__ ushort_t f2bf(float f) {
    union { float f; unsigned u; } v; v.f = f;
    unsigned r = v.u + 0x7FFFu + ((v.u >> 16) & 1u);
    return (ushort_t)(r >> 16);
}
__device__ __forceinline__ float bf2f(ushort_t h) {
    union { unsigned u; float f; } v; v.u = ((unsigned)h) << 16;
    return v.f;
}

__device__ __forceinline__ void gload16(const void* g, void* l) {
    __builtin_amdgcn_global_load_lds(
        (const __attribute__((address_space(1))) void*)g,
        (__attribute__((address_space(3))) void*)l, 16, 0, 0);
}

// ---------------- cast hs+weights -> bf16, fused eta, W1 transpose ----------------
// blocks 0..2047: two hs rows (cast + 16 head-dots via LDS partials); 2048..2815:
// weight cast (slot2 = Wv - Wk); 2816..2831: W1^T -> W1tg (bf16) + W1tf (f32).
// NOTE: eta-in-gemm was tried twice (R11, R16) and regressed the gemm ~10us
// both times; eta stays here. The no-LDS shuffle-dot variant (R13) also lost.
__global__ __launch_bounds__(256) void cast_eta(
    const float* __restrict__ hs, const float* __restrict__ Wq,
    const float* __restrict__ Wk, const float* __restrict__ Wv,
    const float* __restrict__ W1, const float* __restrict__ lrw,
    const float* __restrict__ lrb, ushort_t* __restrict__ hsB,
    ushort_t* __restrict__ Wcat, float* __restrict__ eta,
    ushort_t* __restrict__ W1tg, float* __restrict__ W1tf) {
    __shared__ float pA[16][257], pB[16][257];
    const int bid = blockIdx.x, t = threadIdx.x;
    if (bid < 2048) {
        const int iA = bid * 2, iB = iA + 1;
        const float* rA = hs + (size_t)iA * C_;
        const float* rB = hs + (size_t)iB * C_;
        f32x4 a = *(const f32x4*)(rA + t * 4);
        f32x4 b = *(const f32x4*)(rB + t * 4);
        ushort4_t oa, ob;
        oa.x = f2bf(a.x); oa.y = f2bf(a.y); oa.z = f2bf(a.z); oa.w = f2bf(a.w);
        ob.x = f2bf(b.x); ob.y = f2bf(b.y); ob.z = f2bf(b.z); ob.w = f2bf(b.w);
        *(ushort4_t*)(hsB + (size_t)iA * C_ + t * 4) = oa;
        *(ushort4_t*)(hsB + (size_t)iB * C_ + t * 4) = ob;
        #pragma unroll
        for (int h = 0; h < 16; ++h) {
            f32x4 w = *(const f32x4*)(lrw + (size_t)h * C_ + t * 4);
            pA[h][t] = a.x * w.x + a.y * w.y + a.z * w.z + a.w * w.w;
            pB[h][t] = b.x * w.x + b.y * w.y + b.z * w.z + b.w * w.w;
        }
        __syncthreads();
        const int h = t >> 4, seg = t & 15;
        float sA = 0.f, sB = 0.f;
        #pragma unroll
        for (int j = 0; j < 16; ++j) {
            sA += pA[h][seg * 16 + j];
            sB += pB[h][seg * 16 + j];
        }
        #pragma unroll
        for (int m = 1; m < 16; m <<= 1) {
            sA += __shfl_xor(sA, m, 64);
            sB += __shfl_xor(sB, m, 64);
        }
        if (seg == 0) {
            float bb = lrb[h];
            int bA = iA >> 11, lA = iA & (L_ - 1);
            int bB = iB >> 11, lB = iB & (L_ - 1);
            eta[((size_t)(bA * H_ + h)) * L_ + lA] =
                (1.f / (1.f + expf(-(sA + bb)))) * (1.0f / 64.0f);
            eta[((size_t)(bB * H_ + h)) * L_ + lB] =
                (1.f / (1.f + expf(-(sB + bb)))) * (1.0f / 64.0f);
        }
    } else if (bid < 2816) {
        const int wb = bid - 2048;   // 0..767
        #pragma unroll
        for (int ii = 0; ii < 4; ++ii) {
            int cid = wb * 1024 + ii * 256 + t;      // 0..786431
            int m = cid >> 18, r = cid & ((1 << 18) - 1);
            f32x4 v;
            if (m == 0)      v = *(const f32x4*)(Wq + (size_t)r * 4);
            else if (m == 1) v = *(const f32x4*)(Wk + (size_t)r * 4);
            else {
                f32x4 vv = *(const f32x4*)(Wv + (size_t)r * 4);
                f32x4 vk = *(const f32x4*)(Wk + (size_t)r * 4);
                v.x = vv.x - vk.x; v.y = vv.y - vk.y;
                v.z = vv.z - vk.z; v.w = vv.w - vk.w;
            }
            ushort4_t o;
            o.x = f2bf(v.x); o.y = f2bf(v.y); o.z = f2bf(v.z); o.w = f2bf(v.w);
            *(ushort4_t*)(Wcat + (size_t)m * (C_ * C_) + (size_t)r * 4) = o;
        }
    } else {
        const int h = bid - 2816;    // 0..15
        __shared__ float Wl[64 * 65];
        #pragma unroll
        for (int p = 0; p < 4; ++p) {
            int i4 = p * 256 + t;
            int e = i4 >> 4, f0 = (i4 & 15) * 4;
            f32x4 v = *(const f32x4*)(W1 + (size_t)h * 4096 + e * 64 + f0);
            Wl[(f0 + 0) * 65 + e] = v.x;
            Wl[(f0 + 1) * 65 + e] = v.y;
            Wl[(f0 + 2) * 65 + e] = v.z;
            Wl[(f0 + 3) * 65 + e] = v.w;
        }
        __syncthreads();
        #pragma unroll
        for (int p = 0; p < 16; ++p) {
            int flat = p * 256 + t;           // f*64 + e
            float v = Wl[(flat >> 6) * 65 + (flat & 63)];
            W1tf[(size_t)h * 4096 + flat] = v;
            W1tg[(size_t)h * 4096 + flat] = f2bf(v);
        }
    }
}

// ---------------- projection GEMM: [4096,1024] @ Wcat[3072,1024]^T ----------------
// R4-exact structure: BK=32, 16 KB LDS, one K-tile per barrier pair, 2-way
// pre-swizzle staging, scattered 2B epilogue stores. Fastest measured variant;
// larger-LDS, deeper-pipeline, and eta-tile variants all regressed.
__global__ __launch_bounds__(256) void gemm_qkv(
    const ushort_t* __restrict__ A, const ushort_t* __restrict__ Bc,
    ushort_t* __restrict__ XQ, ushort_t* __restrict__ XK,
    ushort_t* __restrict__ XT) {
    __shared__ __align__(16) ushort_t Al[128 * 32];
    __shared__ __align__(16) ushort_t Bl[128 * 32];
    const int bm = blockIdx.x, bn = blockIdx.y;
    const int t = threadIdx.x, w = t >> 6, lane = t & 63;
    const int wr = w >> 1, wc = w & 1;
    const int la15 = lane & 15, la4 = lane >> 4;
    f32x4 acc[4][4];
    #pragma unroll
    for (int a = 0; a < 4; a++)
        #pragma unroll
        for (int b = 0; b < 4; b++)
            #pragma unroll
            for (int j = 0; j < 4; j++) acc[a][b][j] = 0.f;

    const int ci0 = w * 64 + lane;
    const int xread = (la15 >> 1) & 3;               // read-side swizzle (const/thread)
    const int uslot = la4 ^ xread;                   // swizzled 16B unit for frags

    for (int kt = 0; kt < K_ / 32; ++kt) {
        __syncthreads();
        #pragma unroll
        for (int q = 0; q < 2; ++q) {
            int ci = q * 256 + ci0;
            int r = ci >> 2, kc = ci & 3;
            int kcp = kc ^ ((r >> 1) & 3);           // pre-swizzled source column
            gload16(A + (size_t)(bm * 128 + r) * K_ + kt * 32 + kcp * 8,
                    &Al[q * 2048 + w * 512]);
            gload16(Bc + (size_t)(bn * 128 + r) * K_ + kt * 32 + kcp * 8,
                    &Bl[q * 2048 + w * 512]);
        }
        __syncthreads();
        short8 af[4], bfv[4];
        #pragma unroll
        for (int mf = 0; mf < 4; ++mf)
            af[mf] = *(const short8*)&Al[(wr * 64 + mf * 16 + la15) * 32 + uslot * 8];
        #pragma unroll
        for (int nf = 0; nf < 4; ++nf)
            bfv[nf] = *(const short8*)&Bl[(wc * 64 + nf * 16 + la15) * 32 + uslot * 8];
        #pragma unroll
        for (int mf = 0; mf < 4; ++mf)
            #pragma unroll
            for (int nf = 0; nf < 4; ++nf)
                acc[mf][nf] = __builtin_amdgcn_mfma_f32_16x16x32_bf16(
                    af[mf], bfv[nf], acc[mf][nf], 0, 0, 0);
    }

    const int jbase = bn * 128;
    const int mtx = jbase >> 10;
    ushort_t* dst = (mtx == 0) ? XQ : (mtx == 1 ? XK : XT);
    #pragma unroll
    for (int mf = 0; mf < 4; ++mf)
        #pragma unroll
        for (int nf = 0; nf < 4; ++nf)
            #pragma unroll
            for (int rg = 0; rg < 4; ++rg) {
                int i = bm * 128 + wr * 64 + mf * 16 + (la4 << 2) + rg;
                int j = (jbase & 1023) + wc * 64 + nf * 16 + la15;
                int b = i >> 11, l = i & (L_ - 1);
                int h = j >> 6, d = j & 63;
                dst[((size_t)(b * H_ + h) * L_ + l) * D_ + d] = f2bf(acc[mf][nf][rg]);
            }
}

// ---------------- K2 fused (8 waves, 16 rows/wave for 2x TLP):
//                  Z1 = XK@W1+b1 (W1^T frags from L2), LN-L2-bwd (target = XT,
//                  var = E[x^2]-mu^2), eg = eta*grad, GpT = eg^T@XK, bsump ----
__global__ __launch_bounds__(512) void k2_grad2(
    const ushort_t* __restrict__ XK, const ushort_t* __restrict__ XT,
    const ushort_t* __restrict__ W1tg, const float* __restrict__ b1,
    const float* __restrict__ tw, const float* __restrict__ tb,
    const float* __restrict__ eta, float* __restrict__ GpT,
    float* __restrict__ bsump) {
    __shared__ __align__(16) ushort_t xkt[64 * LDT_];   // XK^T (d-major, l-contig)
    __shared__ __align__(16) ushort_t egl[64 * LDT_];   // eg^T (d-major, l-contig)
    __shared__ float b1s[64], gs[64], bes[64];
    __shared__ float sred[8][64];
    const int bh = blockIdx.y, lt = blockIdx.x;
    const int h = bh & (H_ - 1);
    const int t = threadIdx.x, w = t >> 6, lane = t & 63;
    const int la15 = lane & 15, la4 = lane >> 4;
    if (t < 64) { b1s[t] = b1[h * 64 + t]; gs[t] = tw[h * 64 + t]; bes[t] = tb[h * 64 + t]; }
    __syncthreads();

    const ushort_t* xk = XK + (size_t)bh * L_ * D_;
    const ushort_t* xt = XT + (size_t)bh * L_ * D_;
    const ushort_t* w1g = W1tg + (size_t)h * 4096;
    const int l0 = lt * 128 + w * 16;    // global l base for this wave (16 rows)
    const int llw = w * 16;              // local l base

    f32x4 acc[4];
    #pragma unroll
    for (int nf = 0; nf < 4; nf++) {
        float bv = b1s[nf * 16 + la15];
        #pragma unroll
        for (int j = 0; j < 4; j++) acc[nf][j] = bv;
    }
    #pragma unroll
    for (int ks = 0; ks < 2; ++ks) {
        short8 af, bfv[4];
        const int d0 = ks * 32 + la4 * 8;
        af = *(const short8*)&xk[(size_t)(l0 + la15) * D_ + d0];
        {
            const int ll = llw + la15;
            #pragma unroll
            for (int jj = 0; jj < 8; jj++)
                xkt[(d0 + jj) * LDT_ + ll] = (ushort_t)af[jj];
        }
        #pragma unroll
        for (int nf = 0; nf < 4; nf++)
            bfv[nf] = *(const short8*)&w1g[(nf * 16 + la15) * 64 + d0];
        #pragma unroll
        for (int nf = 0; nf < 4; nf++)
            acc[nf] = __builtin_amdgcn_mfma_f32_16x16x32_bf16(
                af, bfv[nf], acc[nf], 0, 0, 0);
    }

    const float* etap = eta + (size_t)bh * L_;
    float accbs[4] = {0.f, 0.f, 0.f, 0.f};
    #pragma unroll
    for (int rg = 0; rg < 4; ++rg) {
        int lrow = l0 + (la4 << 2) + rg;
        int llr  = llw + (la4 << 2) + rg;
        float x[4], xh[4], gh[4];
        #pragma unroll
        for (int nf = 0; nf < 4; nf++) x[nf] = acc[nf][rg];
        // concurrent sum / sumsq chains (var = E[x^2] - mu^2)
        float s = x[0] + x[1] + x[2] + x[3];
        float q = x[0]*x[0] + x[1]*x[1] + x[2]*x[2] + x[3]*x[3];
        s += __shfl_xor(s, 1, 64); q += __shfl_xor(q, 1, 64);
        s += __shfl_xor(s, 2, 64); q += __shfl_xor(q, 2, 64);
        s += __shfl_xor(s, 4, 64); q += __shfl_xor(q, 4, 64);
        s += __shfl_xor(s, 8, 64); q += __shfl_xor(q, 8, 64);
        float mu = s * (1.f / 64.f);
        float var = q * (1.f / 64.f) - mu * mu;
        float inv = 1.f / sqrtf(var + EPS_);
        float s1 = 0.f, s2 = 0.f;
        #pragma unroll
        for (int nf = 0; nf < 4; nf++) {
            int d = nf * 16 + la15;
            xh[nf] = (x[nf] - mu) * inv;
            float tgt = bf2f(xt[(size_t)lrow * D_ + d]);
            float g = gs[d];
            gh[nf] = (g * xh[nf] + bes[d] - tgt) * g;
            s1 += gh[nf]; s2 += gh[nf] * xh[nf];
        }
        s1 += __shfl_xor(s1, 1, 64); s2 += __shfl_xor(s2, 1, 64);
        s1 += __shfl_xor(s1, 2, 64); s2 += __shfl_xor(s2, 2, 64);
        s1 += __shfl_xor(s1, 4, 64); s2 += __shfl_xor(s2, 4, 64);
        s1 += __shfl_xor(s1, 8, 64); s2 += __shfl_xor(s2, 8, 64);
        float m1 = s1 * (1.f / 64.f), m2 = s2 * (1.f / 64.f);
        float el = etap[lrow];
        #pragma unroll
        for (int nf = 0; nf < 4; nf++) {
            int d = nf * 16 + la15;
            float egv = el * ((gh[nf] - m1 - xh[nf] * m2) * inv);
            accbs[nf] += egv;
            egl[d * LDT_ + llr] = f2bf(egv);
        }
    }
    // wave-local bsum partial: combine the 4 row-groups (lane>>4)
    #pragma unroll
    for (int nf = 0; nf < 4; nf++) {
        accbs[nf] += __shfl_xor(accbs[nf], 16, 64);
        accbs[nf] += __shfl_xor(accbs[nf], 32, 64);
    }
    if (lane < 16)
        #pragma unroll
        for (int nf = 0; nf < 4; nf++) sred[w][nf * 16 + lane] = accbs[nf];
    __syncthreads();

    // G^T partial: GpT[f][e] = sum_l eg[l][f] * XK[l][e] = mfma(A=eg^T, B=XK^T).
    // Waves 0..3 only (16 MFMAs total; waves 4..7 skip).
    if (w < 4) {
        f32x4 aG[4];
        #pragma unroll
        for (int nf = 0; nf < 4; nf++)
            #pragma unroll
            for (int j = 0; j < 4; j++) aG[nf][j] = 0.f;
        #pragma unroll
        for (int ks = 0; ks < 4; ++ks) {
            const int ko = ks * 32 + la4 * 8;
            short8 ae = *(const short8*)&egl[(w * 16 + la15) * LDT_ + ko];
            #pragma unroll
            for (int nf = 0; nf < 4; nf++) {
                short8 be = *(const short8*)&xkt[(nf * 16 + la15) * LDT_ + ko];
                aG[nf] = __builtin_amdgcn_mfma_f32_16x16x32_bf16(ae, be, aG[nf], 0, 0, 0);
            }
        }
        float* gp = GpT + (size_t)(bh * NCHUNK_ + lt) * 4096;
        #pragma unroll
        for (int nf = 0; nf < 4; nf++)
            #pragma unroll
            for (int rg = 0; rg < 4; rg++) {
                int f = w * 16 + (la4 << 2) + rg;
                int e = nf * 16 + la15;
                gp[f * 64 + e] = aG[nf][rg];
            }
    }
    if (t < 64) {
        float s = 0.f;
        #pragma unroll
        for (int ww = 0; ww < 8; ww++) s += sred[ww][t];
        bsump[(bh * NCHUNK_ + lt) * 64 + t] = s;
    }
}

// ---------------- K2b-reduce: G = sum_c GpT, bsum = sum_c bsump (fixed order) ----
__global__ __launch_bounds__(256) void k2b_reduce(
    const float* __restrict__ GpT, const float* __restrict__ bsump,
    float* __restrict__ G, float* __restrict__ bsum) {
    const int seg = blockIdx.x, bh = blockIdx.y;   // seg in [0,8)
    const int t = threadIdx.x;
    #pragma unroll 2
    for (int ii = 0; ii < 2; ++ii) {
        int i = seg * 512 + ii * 256 + t;
        float s = 0.f;
        #pragma unroll
        for (int c = 0; c < NCHUNK_; c++)
            s += GpT[(size_t)(bh * NCHUNK_ + c) * 4096 + i];
        G[(size_t)bh * 4096 + i] = s;
    }
    if (seg == 0 && t < 64) {
        float s = 0.f;
        #pragma unroll
        for (int c = 0; c < NCHUNK_; c++)
            s += bsump[(bh * NCHUNK_ + c) * 64 + t];
        bsum[bh * 64 + t] = s;
    }
}

// ---------------- K3 (8 waves, 16 rows/wave for 2x TLP):
//                  Wt = W1^T - G^T (linear fill, stride-72 pad),
//                  Z1b = XQ@Wt + b1bar, LN-fwd, out = XQ + LN ----------------
__global__ __launch_bounds__(512) void k3_out(
    const ushort_t* __restrict__ XQ, const float* __restrict__ W1tf,
    const float* __restrict__ G, const float* __restrict__ b1,
    const float* __restrict__ bsum, const float* __restrict__ tw,
    const float* __restrict__ tb, float* __restrict__ out) {
    __shared__ __align__(16) ushort_t Wt[64 * WTS_];
    __shared__ float b1s[64], gs[64], bes[64];
    const int bh = blockIdx.y, lt = blockIdx.x;
    const int h = bh & (H_ - 1);
    const int t = threadIdx.x, w = t >> 6, lane = t & 63;
    const int la15 = lane & 15, la4 = lane >> 4;
    for (int p = t; p < 4096; p += 512) {
        float s = W1tf[(size_t)h * 4096 + p] - G[(size_t)bh * 4096 + p];
        Wt[(p >> 6) * WTS_ + (p & 63)] = f2bf(s);
    }
    if (t < 64) {
        b1s[t] = b1[h * 64 + t] - bsum[bh * 64 + t];
        gs[t] = tw[h * 64 + t]; bes[t] = tb[h * 64 + t];
    }
    __syncthreads();

    const ushort_t* xq = XQ + (size_t)bh * L_ * D_;
    const int l0 = lt * 128 + w * 16;
    f32x4 acc[4];
    #pragma unroll
    for (int nf = 0; nf < 4; nf++) {
        float bv = b1s[nf * 16 + la15];
        #pragma unroll
        for (int j = 0; j < 4; j++) acc[nf][j] = bv;
    }
    #pragma unroll
    for (int ks = 0; ks < 2; ++ks) {
        short8 af, bfv[4];
        const int d0 = ks * 32 + la4 * 8;
        af = *(const short8*)&xq[(size_t)(l0 + la15) * D_ + d0];
        #pragma unroll
        for (int nf = 0; nf < 4; nf++)
            bfv[nf] = *(const short8*)&Wt[(nf * 16 + la15) * WTS_ + d0];
        #pragma unroll
        for (int nf = 0; nf < 4; nf++)
            acc[nf] = __builtin_amdgcn_mfma_f32_16x16x32_bf16(
                af, bfv[nf], acc[nf], 0, 0, 0);
    }

    float* outp = out + (size_t)bh * L_ * D_;
    #pragma unroll
    for (int rg = 0; rg < 4; ++rg) {
        int lrow = l0 + (la4 << 2) + rg;
        float x[4];
        #pragma unroll
        for (int nf = 0; nf < 4; nf++) x[nf] = acc[nf][rg];
        float s = x[0] + x[1] + x[2] + x[3];
        float q = x[0]*x[0] + x[1]*x[1] + x[2]*x[2] + x[3]*x[3];
        s += __shfl_xor(s, 1, 64); q += __shfl_xor(q, 1, 64);
        s += __shfl_xor(s, 2, 64); q += __shfl_xor(q, 2, 64);
        s += __shfl_xor(s, 4, 64); q += __shfl_xor(q, 4, 64);
        s += __shfl_xor(s, 8, 64); q += __shfl_xor(q, 8, 64);
        float mu = s * (1.f / 64.f);
        float var = q * (1.f / 64.f) - mu * mu;
        float inv = 1.f / sqrtf(var + EPS_);
        #pragma unroll
        for (int nf = 0; nf < 4; nf++) {
            int d = nf * 16 + la15;
            float xh = (x[nf] - mu) * inv;
            float o = gs[d] * xh + bes[d];
            float qv = bf2f(xq[(size_t)lrow * D_ + d]);
            outp[(size_t)lrow * D_ + d] = qv + o;
        }
    }
}

extern "C" void kernel_launch(void* const* d_in, const int* in_sizes, int n_in,
                              void* d_out, int out_size, void* d_ws, size_t ws_size,
                              hipStream_t stream) {
    const float* hs  = (const float*)d_in[0];
    const float* Wq  = (const float*)d_in[1];
    const float* Wk  = (const float*)d_in[2];
    const float* Wv  = (const float*)d_in[3];
    const float* W1  = (const float*)d_in[4];
    const float* b1  = (const float*)d_in[5];
    const float* tw  = (const float*)d_in[6];
    const float* tb  = (const float*)d_in[7];
    const float* lrw = (const float*)d_in[8];
    const float* lrb = (const float*)d_in[9];
    float* out = (float*)d_out;

    char* ws = (char*)d_ws;
    size_t off = 0;
    ushort_t* hsB  = (ushort_t*)(ws + off); off += (size_t)M_ * K_ * 2;   // 8 MB
    ushort_t* Wcat = (ushort_t*)(ws + off); off += (size_t)N_ * K_ * 2;   // 6 MB
    ushort_t* XQ   = (ushort_t*)(ws + off); off += (size_t)M_ * C_ * 2;
    ushort_t* XK   = (ushort_t*)(ws + off); off += (size_t)M_ * C_ * 2;
    ushort_t* XT   = (ushort_t*)(ws + off); off += (size_t)M_ * C_ * 2;   // recon target
    float*    eta  = (float*)(ws + off);    off += (size_t)BH_ * L_ * 4;
    ushort_t* W1tg = (ushort_t*)(ws + off); off += (size_t)H_ * D_ * D_ * 2;  // bf16 W1^T
    float*    W1tf = (float*)(ws + off);    off += (size_t)H_ * D_ * D_ * 4;  // f32 W1^T
    float*    G    = (float*)(ws + off);    off += (size_t)BH_ * D_ * D_ * 4; // reduced G^T
    float*    bsum = (float*)(ws + off);    off += (size_t)BH_ * D_ * 4;
    // Partial buffers overlay hsB/Wcat: both dead after gemm_qkv; k2_grad2
    // writes them strictly later on the same stream.
    float*    GpT   = (float*)hsB;   // 32*16*4096*4 = 8 MB == sizeof(hsB)
    float*    bsump = (float*)Wcat;  // 128 KB << 6 MB

    cast_eta<<<2048 + 768 + 16, 256, 0, stream>>>(hs, Wq, Wk, Wv, W1, lrw, lrb,
                                                  hsB, Wcat, eta, W1tg, W1tf);
    gemm_qkv<<<dim3(M_ / 128, N_ / 128), 256, 0, stream>>>(hsB, Wcat, XQ, XK, XT);
    k2_grad2<<<dim3(L_ / 128, BH_), 512, 0, stream>>>(XK, XT, W1tg, b1, tw, tb, eta, GpT, bsump);
    k2b_reduce<<<dim3(8, BH_), 256, 0, stream>>>(GpT, bsump, G, bsum);
    k3_out<<<dim3(L_ / 128, BH_), 512, 0, stream>>>(XQ, W1tf, G, b1, bsum, tw, tb, out);
}